// Round 8
// baseline (129.429 us; speedup 1.0000x reference)
//
#include <hip/hip_runtime.h>

#define K_TOP 205
#define ROW   4096
#define NTHR  256
#define RPB   4              // rows per block, one row per wave
#define CAP   256            // candidate slots per wave (M: mean 169, sd 12.7; +6.8 sigma)
#define NSLOT (CAP / 64)     // 4

#define FLO 1.45f            // candidate window brackets the 95th pct of N(0,1)
#define FHI 1.85f

typedef float fx4 __attribute__((ext_vector_type(4)));

__device__ __forceinline__ unsigned key_of_bits(unsigned b) {
    return b ^ (((unsigned)((int)b >> 31)) | 0x80000000u);
}
__device__ __forceinline__ float val_of(unsigned u) {
    return __uint_as_float(u ^ ((u & 0x80000000u) ? 0x80000000u : 0xFFFFFFFFu));
}
__device__ __forceinline__ unsigned wave_sum(unsigned v) {
#pragma unroll
    for (int off = 1; off < 64; off <<= 1) v += __shfl_xor(v, off, 64);
    return v;
}
__device__ __forceinline__ unsigned mbcnt64(unsigned long long m) {
    return __builtin_amdgcn_mbcnt_hi((unsigned)(m >> 32),
           __builtin_amdgcn_mbcnt_lo((unsigned)m, 0u));
}

// ---------------- K1: per-row threshold (CACHED reads -> L3 stays hot) ----------------
__global__ __launch_bounds__(NTHR, 8)
void kwta_thresh(const float* __restrict__ x, uint4* __restrict__ rec) {
    __shared__ float cand[RPB][CAP];

    const int lane = (int)(threadIdx.x & 63u);
    const int wave = (int)(threadIdx.x >> 6u);
    const long long row = (long long)blockIdx.x * RPB + wave;
    const fx4* __restrict__ xin = (const fx4*)(x + row * (long long)ROW);

#pragma unroll
    for (int s = 0; s < NSLOT; ++s) cand[wave][lane + 64 * s] = 0.0f;

    unsigned base = 0, chi = 0;
#pragma unroll
    for (int j = 0; j < 16; ++j) {
        fx4 v = xin[j * 64 + lane];          // cached on purpose: populate L3 for K2
#pragma unroll
        for (int c = 0; c < 4; ++c) {
            float e = v[c];
            unsigned long long mhi = __ballot(e >= FHI);
            unsigned long long mlo = __ballot(e >= FLO);
            unsigned long long mw  = mlo & ~mhi;
            if (e >= FLO && e < FHI) {
                unsigned slot = base + mbcnt64(mw);
                if (slot < CAP) cand[wave][slot] = e;
            }
            base += (unsigned)__popcll(mw);
            chi  += (unsigned)__popcll(mhi);
        }
    }
    const unsigned M = base, c_hi = chi, c_lo = base + chi;

    float Tf; unsigned S, Sex;
    const bool fast = (c_lo >= K_TOP) && (c_hi < K_TOP) && (M <= CAP);
    if (fast) {
        float cs[NSLOT];
#pragma unroll
        for (int s = 0; s < NSLOT; ++s) cs[s] = cand[wave][lane + 64 * s];

        // interpolated bisect on positive-float bit grid; early exit at cl==K
        unsigned lo = __float_as_uint(FLO), hi = __float_as_uint(FHI);
        unsigned cl = c_lo, ch = c_hi;
        int it = 0;
        while (hi - lo > 1u && cl != K_TOP) {
            unsigned span = hi - lo, off;
            if ((it & 1) == 0) {
                float frac = (float)(cl - K_TOP) / (float)(cl - ch);
                off = (unsigned)((float)span * frac);
            } else {
                off = span >> 1;
            }
            if (off < 1u) off = 1u;
            if (off > span - 1u) off = span - 1u;
            unsigned mid = lo + off;
            float mf = __uint_as_float(mid);
            unsigned c = c_hi;
#pragma unroll
            for (int s = 0; s < NSLOT; ++s)
                c += (unsigned)__popcll(__ballot(cs[s] >= mf));
            if (c >= K_TOP) { lo = mid; cl = c; } else { hi = mid; ch = c; }
            ++it;
        }
        Tf = __uint_as_float(lo); S = cl; Sex = ch;
    } else {
        // rare exact fallback: full-key bisection, re-reading the row (L2/L3 hits)
        unsigned lo = 0u, hi = 0xFFFFFFFFu, cl = ROW, ch;
        {
            unsigned cc = 0;
            for (int j = 0; j < 16; ++j) {
                fx4 v = xin[j * 64 + lane];
#pragma unroll
                for (int c = 0; c < 4; ++c)
                    cc += (unsigned)(key_of_bits(__float_as_uint(v[c])) >= hi);
            }
            ch = wave_sum(cc);
        }
        if (ch >= K_TOP) { lo = hi; cl = ch; ch = 0; }
        else {
            while (hi - lo > 1u && cl != K_TOP) {
                asm volatile("" ::: "memory");
                unsigned mid = lo + ((hi - lo) >> 1);
                unsigned cc = 0;
                for (int j = 0; j < 16; ++j) {
                    fx4 v = xin[j * 64 + lane];
#pragma unroll
                    for (int c = 0; c < 4; ++c)
                        cc += (unsigned)(key_of_bits(__float_as_uint(v[c])) >= mid);
                }
                cc = wave_sum(cc);
                if (cc >= K_TOP) { lo = mid; cl = cc; } else { hi = mid; ch = cc; }
            }
        }
        Tf = val_of(lo); S = cl; Sex = ch;
    }

    if (lane == 0) rec[row] = make_uint4(__float_as_uint(Tf), S, Sex, 0u);
}

// ---------------- K2: apply mask (reads should hit L3; NT stores) ----------------
__global__ __launch_bounds__(NTHR, 8)
void kwta_apply(const float* __restrict__ x, const uint4* __restrict__ rec,
                float* __restrict__ out) {
    const int lane = (int)(threadIdx.x & 63u);
    const int wave = (int)(threadIdx.x >> 6u);
    const long long row = (long long)blockIdx.x * RPB + wave;
    const fx4* __restrict__ xin = (const fx4*)(x + row * (long long)ROW);
    fx4* __restrict__ o = (fx4*)(out + row * (long long)ROW);

    const uint4 R = rec[row];                // 16B broadcast, L2-resident
    const float Tf = __uint_as_float(R.x);
    const unsigned S = R.y, Sex = R.z;

    if (S == K_TOP) {
        // common case: pure masked copy, zero cross-lane work
#pragma unroll
        for (int j = 0; j < 16; ++j) {
            fx4 v = xin[j * 64 + lane], w;
            w.x = (v.x >= Tf) ? v.x : 0.0f;
            w.y = (v.y >= Tf) ? v.y : 0.0f;
            w.z = (v.z >= Tf) ? v.z : 0.0f;
            w.w = (v.w >= Tf) ? v.w : 0.0f;
            __builtin_nontemporal_store(w, &o[j * 64 + lane]);
        }
    } else {
        // rare: ties at Tf — rank by flat index (j, lane, c), keep first r
        const unsigned r = K_TOP - Sex;
        unsigned rank_base = 0;
        for (int j = 0; j < 16; ++j) {
            fx4 v = xin[j * 64 + lane];
            unsigned e = (unsigned)(v.x == Tf) + (unsigned)(v.y == Tf)
                       + (unsigned)(v.z == Tf) + (unsigned)(v.w == Tf);
            unsigned inc = e;
#pragma unroll
            for (int off = 1; off < 64; off <<= 1) {
                unsigned n = __shfl_up(inc, off, 64);
                if (lane >= off) inc += n;
            }
            unsigned rk  = rank_base + (inc - e);
            unsigned tot = __shfl(inc, 63, 64);

            fx4 w;
            if (v.x == Tf) { w.x = (rk < r) ? v.x : 0.0f; ++rk; }
            else           { w.x = (v.x > Tf) ? v.x : 0.0f; }
            if (v.y == Tf) { w.y = (rk < r) ? v.y : 0.0f; ++rk; }
            else           { w.y = (v.y > Tf) ? v.y : 0.0f; }
            if (v.z == Tf) { w.z = (rk < r) ? v.z : 0.0f; ++rk; }
            else           { w.z = (v.z > Tf) ? v.z : 0.0f; }
            if (v.w == Tf) { w.w = (rk < r) ? v.w : 0.0f; ++rk; }
            else           { w.w = (v.w > Tf) ? v.w : 0.0f; }
            __builtin_nontemporal_store(w, &o[j * 64 + lane]);

            rank_base += tot;
        }
    }
}

// ---------------- fused fallback (round-7 kernel) if ws_size is too small ----------------
__global__ __launch_bounds__(NTHR, 4)
void kwta_fused(const float* __restrict__ x, float* __restrict__ out) {
    __shared__ float cand[RPB][CAP];
    const int lane = (int)(threadIdx.x & 63u);
    const int wave = (int)(threadIdx.x >> 6u);
    const long long row = (long long)blockIdx.x * RPB + wave;
    const fx4* __restrict__ xin = (const fx4*)(x + row * (long long)ROW);
    fx4* __restrict__ o = (fx4*)(out + row * (long long)ROW);

#pragma unroll
    for (int s = 0; s < NSLOT; ++s) cand[wave][lane + 64 * s] = 0.0f;

    fx4 f[16];
    unsigned base = 0, chi = 0;
#pragma unroll
    for (int j = 0; j < 16; ++j) {
        fx4 v = __builtin_nontemporal_load(&xin[j * 64 + lane]);
        f[j] = v;
#pragma unroll
        for (int c = 0; c < 4; ++c) {
            float e = v[c];
            unsigned long long mhi = __ballot(e >= FHI);
            unsigned long long mlo = __ballot(e >= FLO);
            unsigned long long mw  = mlo & ~mhi;
            if (e >= FLO && e < FHI) {
                unsigned slot = base + mbcnt64(mw);
                if (slot < CAP) cand[wave][slot] = e;
            }
            base += (unsigned)__popcll(mw);
            chi  += (unsigned)__popcll(mhi);
        }
    }
    const unsigned M = base, c_hi = chi, c_lo = base + chi;

    float Tf; unsigned S, Sex;
    const bool fast = (c_lo >= K_TOP) && (c_hi < K_TOP) && (M <= CAP);
    if (fast) {
        float cs[NSLOT];
#pragma unroll
        for (int s = 0; s < NSLOT; ++s) cs[s] = cand[wave][lane + 64 * s];
        unsigned lo = __float_as_uint(FLO), hi = __float_as_uint(FHI);
        unsigned cl = c_lo, ch = c_hi;
        int it = 0;
        while (hi - lo > 1u && cl != K_TOP) {
            unsigned span = hi - lo, off;
            if ((it & 1) == 0) {
                float frac = (float)(cl - K_TOP) / (float)(cl - ch);
                off = (unsigned)((float)span * frac);
            } else off = span >> 1;
            if (off < 1u) off = 1u;
            if (off > span - 1u) off = span - 1u;
            unsigned mid = lo + off;
            float mf = __uint_as_float(mid);
            unsigned c = c_hi;
#pragma unroll
            for (int s = 0; s < NSLOT; ++s)
                c += (unsigned)__popcll(__ballot(cs[s] >= mf));
            if (c >= K_TOP) { lo = mid; cl = c; } else { hi = mid; ch = c; }
            ++it;
        }
        Tf = __uint_as_float(lo); S = cl; Sex = ch;
    } else {
        unsigned lo = 0u, hi = 0xFFFFFFFFu, cl = ROW, ch;
        {
            unsigned cc = 0;
#pragma unroll
            for (int j = 0; j < 16; ++j)
                for (int c = 0; c < 4; ++c)
                    cc += (unsigned)(key_of_bits(__float_as_uint(f[j][c])) >= hi);
            ch = wave_sum(cc);
        }
        if (ch >= K_TOP) { lo = hi; cl = ch; ch = 0; }
        else {
            while (hi - lo > 1u && cl != K_TOP) {
                unsigned mid = lo + ((hi - lo) >> 1);
                unsigned cc = 0;
#pragma unroll
                for (int j = 0; j < 16; ++j)
                    for (int c = 0; c < 4; ++c)
                        cc += (unsigned)(key_of_bits(__float_as_uint(f[j][c])) >= mid);
                cc = wave_sum(cc);
                if (cc >= K_TOP) { lo = mid; cl = cc; } else { hi = mid; ch = cc; }
            }
        }
        Tf = val_of(lo); S = cl; Sex = ch;
    }

    if (S == K_TOP) {
#pragma unroll
        for (int j = 0; j < 16; ++j) {
            fx4 v = f[j], w;
            w.x = (v.x >= Tf) ? v.x : 0.0f;
            w.y = (v.y >= Tf) ? v.y : 0.0f;
            w.z = (v.z >= Tf) ? v.z : 0.0f;
            w.w = (v.w >= Tf) ? v.w : 0.0f;
            __builtin_nontemporal_store(w, &o[j * 64 + lane]);
        }
    } else {
        const unsigned r = K_TOP - Sex;
        unsigned rank_base = 0;
        for (int j = 0; j < 16; ++j) {
            fx4 v = f[j];
            unsigned e = (unsigned)(v.x == Tf) + (unsigned)(v.y == Tf)
                       + (unsigned)(v.z == Tf) + (unsigned)(v.w == Tf);
            unsigned inc = e;
#pragma unroll
            for (int off = 1; off < 64; off <<= 1) {
                unsigned n = __shfl_up(inc, off, 64);
                if (lane >= off) inc += n;
            }
            unsigned rk  = rank_base + (inc - e);
            unsigned tot = __shfl(inc, 63, 64);
            fx4 w;
            if (v.x == Tf) { w.x = (rk < r) ? v.x : 0.0f; ++rk; }
            else           { w.x = (v.x > Tf) ? v.x : 0.0f; }
            if (v.y == Tf) { w.y = (rk < r) ? v.y : 0.0f; ++rk; }
            else           { w.y = (v.y > Tf) ? v.y : 0.0f; }
            if (v.z == Tf) { w.z = (rk < r) ? v.z : 0.0f; ++rk; }
            else           { w.z = (v.z > Tf) ? v.z : 0.0f; }
            if (v.w == Tf) { w.w = (rk < r) ? v.w : 0.0f; ++rk; }
            else           { w.w = (v.w > Tf) ? v.w : 0.0f; }
            __builtin_nontemporal_store(w, &o[j * 64 + lane]);
            rank_base += tot;
        }
    }
}

extern "C" void kernel_launch(void* const* d_in, const int* in_sizes, int n_in,
                              void* d_out, int out_size, void* d_ws, size_t ws_size,
                              hipStream_t stream) {
    const float* x = (const float*)d_in[0];
    float* out = (float*)d_out;
    const int rows = out_size / ROW;     // 16384

    if (ws_size >= (size_t)rows * sizeof(uint4)) {
        uint4* rec = (uint4*)d_ws;
        kwta_thresh<<<rows / RPB, NTHR, 0, stream>>>(x, rec);
        kwta_apply <<<rows / RPB, NTHR, 0, stream>>>(x, rec, out);
    } else {
        kwta_fused <<<rows / RPB, NTHR, 0, stream>>>(x, out);
    }
}

// Round 9
// 109.702 us; speedup vs baseline: 1.1798x; 1.1798x over previous
//
#include <hip/hip_runtime.h>

#define K_TOP 205
#define ROW   4096
#define NTHR  256
#define RPB   4              // rows per block, one row per wave
#define CAP   256            // candidate slots per wave (M: mean 169, sd 12.7; 256 = +6.8 sigma)
#define NSLOT (CAP / 64)     // 4

#define FLO 1.45f            // candidate window brackets the 95th pct of N(0,1)
#define FHI 1.85f

typedef float fx4 __attribute__((ext_vector_type(4)));

__device__ __forceinline__ unsigned key_of_bits(unsigned b) {
    return b ^ (((unsigned)((int)b >> 31)) | 0x80000000u);
}
__device__ __forceinline__ float val_of(unsigned u) {
    return __uint_as_float(u ^ ((u & 0x80000000u) ? 0x80000000u : 0xFFFFFFFFu));
}
__device__ __forceinline__ unsigned wave_sum(unsigned v) {
#pragma unroll
    for (int off = 1; off < 64; off <<= 1) v += __shfl_xor(v, off, 64);
    return v;
}
// popcount(mask & lanes_below_me): 2 VALU ops
__device__ __forceinline__ unsigned mbcnt64(unsigned long long m) {
    return __builtin_amdgcn_mbcnt_hi((unsigned)(m >> 32),
           __builtin_amdgcn_mbcnt_lo((unsigned)m, 0u));
}

__global__ __launch_bounds__(NTHR, 4)
void kwta_kernel(const float* __restrict__ x, float* __restrict__ out) {
    __shared__ float cand[RPB][CAP];

    const int lane = (int)(threadIdx.x & 63u);
    const int wave = (int)(threadIdx.x >> 6u);
    const long long row = (long long)blockIdx.x * RPB + wave;

    const fx4* __restrict__ xin = (const fx4*)(x + row * (long long)ROW);
    fx4* __restrict__ o = (fx4*)(out + row * (long long)ROW);

    // zero candidate slots (per-wave private; 0 < FLO never counts)
#pragma unroll
    for (int s = 0; s < NSLOT; ++s) cand[wave][lane + 64 * s] = 0.0f;

    // ---- load row to registers; ballot-stats + ballot/mbcnt compaction ----
    fx4 f[16];
    unsigned base = 0, chi = 0;          // uniform (SGPR): window count, #(>=FHI)
#pragma unroll
    for (int j = 0; j < 16; ++j) {
        fx4 v = __builtin_nontemporal_load(&xin[j * 64 + lane]);
        f[j] = v;
        float es[4] = {v.x, v.y, v.z, v.w};
#pragma unroll
        for (int c = 0; c < 4; ++c) {
            float e = es[c];
            unsigned long long mhi = __ballot(e >= FHI);
            unsigned long long mlo = __ballot(e >= FLO);
            unsigned long long mw  = mlo & ~mhi;
            if (e >= FLO && e < FHI) {
                unsigned slot = base + mbcnt64(mw);
                if (slot < CAP) cand[wave][slot] = e;   // guard: no OOB
            }
            base += (unsigned)__popcll(mw);             // SALU chain, ~2cy/step
            chi  += (unsigned)__popcll(mhi);
        }
    }
    const unsigned M    = base;
    const unsigned c_hi = chi;
    const unsigned c_lo = base + chi;

    float Tf; unsigned S, Sex;           // threshold, cnt(>=Tf), cnt(>Tf)

    const bool fast = (c_lo >= K_TOP) && (c_hi < K_TOP) && (M <= CAP);
    if (fast) {
        float cs[NSLOT];
#pragma unroll
        for (int s = 0; s < NSLOT; ++s) cs[s] = cand[wave][lane + 64 * s];

        // interpolated bisect on positive-float bit grid; early exit at cl==K.
        // (any T with cnt(>=T)==K masks the exact top-K set)
        unsigned lo = __float_as_uint(FLO), hi = __float_as_uint(FHI);
        unsigned cl = c_lo, ch = c_hi;
        int it = 0;
        while (hi - lo > 1u && cl != K_TOP) {
            unsigned span = hi - lo, off;
            if ((it & 1) == 0) {         // regula falsi on near-affine CDF
                float frac = (float)(cl - K_TOP) / (float)(cl - ch);
                off = (unsigned)((float)span * frac);
            } else {                     // safeguard: alternate with midpoint
                off = span >> 1;
            }
            if (off < 1u) off = 1u;
            if (off > span - 1u) off = span - 1u;
            unsigned mid = lo + off;
            float mf = __uint_as_float(mid);
            unsigned c = c_hi;
#pragma unroll
            for (int s = 0; s < NSLOT; ++s)
                c += (unsigned)__popcll(__ballot(cs[s] >= mf));
            if (c >= K_TOP) { lo = mid; cl = c; } else { hi = mid; ch = c; }
            ++it;
        }
        Tf = __uint_as_float(lo); S = cl; Sex = ch;
    } else {
        // ---- rare exact fallback: full-key bisection over register row ----
        unsigned lo = 0u, hi = 0xFFFFFFFFu, cl = ROW, ch;
        {
            unsigned cc = 0;
#pragma unroll
            for (int j = 0; j < 16; ++j) {
                cc += (unsigned)(key_of_bits(__float_as_uint(f[j].x)) >= hi)
                    + (unsigned)(key_of_bits(__float_as_uint(f[j].y)) >= hi)
                    + (unsigned)(key_of_bits(__float_as_uint(f[j].z)) >= hi)
                    + (unsigned)(key_of_bits(__float_as_uint(f[j].w)) >= hi);
            }
            ch = wave_sum(cc);
        }
        if (ch >= K_TOP) { lo = hi; cl = ch; ch = 0; }
        else {
            while (hi - lo > 1u && cl != K_TOP) {
                unsigned mid = lo + ((hi - lo) >> 1);
                unsigned cc = 0;
#pragma unroll
                for (int j = 0; j < 16; ++j) {
                    cc += (unsigned)(key_of_bits(__float_as_uint(f[j].x)) >= mid)
                        + (unsigned)(key_of_bits(__float_as_uint(f[j].y)) >= mid)
                        + (unsigned)(key_of_bits(__float_as_uint(f[j].z)) >= mid)
                        + (unsigned)(key_of_bits(__float_as_uint(f[j].w)) >= mid);
                }
                cc = wave_sum(cc);
                if (cc >= K_TOP) { lo = mid; cl = cc; } else { hi = mid; ch = cc; }
            }
        }
        Tf = val_of(lo); S = cl; Sex = ch;
    }

    if (S == K_TOP) {
        // common case: mask >= Tf keeps exactly K elements
#pragma unroll
        for (int j = 0; j < 16; ++j) {
            fx4 v = f[j], w;
            w.x = (v.x >= Tf) ? v.x : 0.0f;
            w.y = (v.y >= Tf) ? v.y : 0.0f;
            w.z = (v.z >= Tf) ? v.z : 0.0f;
            w.w = (v.w >= Tf) ? v.w : 0.0f;
            __builtin_nontemporal_store(w, &o[j * 64 + lane]);
        }
    } else {
        // rare: ties at Tf — rank by flat index (j, lane, c), keep first r
        const unsigned r = K_TOP - Sex;
        unsigned rank_base = 0;
        for (int j = 0; j < 16; ++j) {
            fx4 v = f[j];
            unsigned e = (unsigned)(v.x == Tf) + (unsigned)(v.y == Tf)
                       + (unsigned)(v.z == Tf) + (unsigned)(v.w == Tf);
            unsigned inc = e;
#pragma unroll
            for (int off = 1; off < 64; off <<= 1) {
                unsigned n = __shfl_up(inc, off, 64);
                if (lane >= off) inc += n;
            }
            unsigned rk  = rank_base + (inc - e);        // exclusive prefix
            unsigned tot = __shfl(inc, 63, 64);          // chunk total

            fx4 w;
            if (v.x == Tf) { w.x = (rk < r) ? v.x : 0.0f; ++rk; }
            else           { w.x = (v.x > Tf) ? v.x : 0.0f; }
            if (v.y == Tf) { w.y = (rk < r) ? v.y : 0.0f; ++rk; }
            else           { w.y = (v.y > Tf) ? v.y : 0.0f; }
            if (v.z == Tf) { w.z = (rk < r) ? v.z : 0.0f; ++rk; }
            else           { w.z = (v.z > Tf) ? v.z : 0.0f; }
            if (v.w == Tf) { w.w = (rk < r) ? v.w : 0.0f; ++rk; }
            else           { w.w = (v.w > Tf) ? v.w : 0.0f; }
            __builtin_nontemporal_store(w, &o[j * 64 + lane]);

            rank_base += tot;
        }
    }
}

extern "C" void kernel_launch(void* const* d_in, const int* in_sizes, int n_in,
                              void* d_out, int out_size, void* d_ws, size_t ws_size,
                              hipStream_t stream) {
    const float* x = (const float*)d_in[0];
    float* out = (float*)d_out;
    const int rows = out_size / ROW;     // 16384
    kwta_kernel<<<rows / RPB, NTHR, 0, stream>>>(x, out);
}